// Round 7
// baseline (587.874 us; speedup 1.0000x reference)
//
#include <hip/hip_runtime.h>

#define TPB     256
#define CCL_TPB 1024
#define S_PIX   4096   // 64*64
#define NCH     256
#define NB      64
#define MAXC    1024   // max 8-connected comps in 64x64
#define KP      15     // K*P
#define CPB     4      // channels per accum block
#define NCHUNK  (NCH / CPB)   // 64

// ---------------- K0: normalize SFC prototypes ----------------
__global__ __launch_bounds__(TPB) void sfc_norm_kernel(
    const float* __restrict__ sfc, float* __restrict__ sn)
{
    int t = threadIdx.x;
    int kp = t >> 4, l = t & 15;
    if (kp < KP) {
        const float* v = sfc + kp * NCH;
        float s = 0.f;
        for (int c = l; c < NCH; c += 16) { float x = v[c]; s += x * x; }
        #pragma unroll
        for (int m = 8; m >= 1; m >>= 1) s += __shfl_xor(s, m, 16);
        float inv = 1.f / fmaxf(sqrtf(s), 1e-12f);
        for (int c = l; c < NCH; c += 16) sn[kp * NCH + c] = v[c] * inv;
    }
}

// ---------------- K1: union-find CCL, run-init + path-halving ----------------
__device__ __forceinline__ int uf_find(int* lab, int x) {
    int p = lab[x];
    for (;;) {
        int gp = lab[p];
        if (gp == p) return p;
        atomicMin(&lab[x], gp);   // path halving; monotone-safe
        x = p; p = gp;
    }
}
__device__ __forceinline__ void uf_merge(int* lab, int a, int b) {
    for (;;) {
        a = uf_find(lab, a);
        b = uf_find(lab, b);
        if (a == b) return;
        int mx = a > b ? a : b;
        int mn = a > b ? b : a;
        int old = atomicMin(&lab[mx], mn);
        if (old == mx) return;
        a = old; b = mn;
    }
}

__global__ __launch_bounds__(CCL_TPB) void ccl_uf_kernel(
    const int* __restrict__ mask, int* __restrict__ cid,
    int* __restrict__ ncomp, int* __restrict__ gcomp)
{
    __shared__ int lab[S_PIX];
    __shared__ int sz[S_PIX];
    __shared__ int rid[S_PIX];
    __shared__ int cnt, gpack;
    const int b = blockIdx.x, t = threadIdx.x;
    const int wave = t >> 6, lane = t & 63;
    const int* mb = mask + b * S_PIX;

    // run-start initial labels: one wave per row (rows strided by 16)
    for (int r = wave; r < 64; r += 16) {
        bool fg = mb[r * 64 + lane] > 0;
        unsigned long long bits = __ballot(fg);
        int labv = -1;
        if (fg) {
            unsigned long long zeros = ~bits;
            unsigned long long below = (lane == 63) ? zeros
                                     : (zeros & ((1ull << (lane + 1)) - 1));
            int start = (below == 0) ? 0 : (64 - __clzll(below));
            labv = r * 64 + start;
        }
        lab[r * 64 + lane] = labv;
        sz[r * 64 + lane] = 0;
    }
    if (t == 0) { cnt = 0; gpack = -1; }
    __syncthreads();

    // merges to the row above only; decision tree skips redundant ones
    for (int i = t + 64; i < S_PIX; i += CCL_TPB) {
        if (lab[i] < 0) continue;
        int x = i & 63;
        bool nf  = lab[i - 64] >= 0;
        bool nwf = x > 0  && lab[i - 65] >= 0;
        bool nef = x < 63 && lab[i - 63] >= 0;
        bool wf  = x > 0  && lab[i - 1]  >= 0;
        if (nf) {
            if (!(wf && nwf)) uf_merge(lab, i, i - 64);
        } else {
            if (nwf) uf_merge(lab, i, i - 65);
            if (nef) uf_merge(lab, i, i - 63);
        }
    }
    __syncthreads();

    // compression + sizes
    for (int i = t; i < S_PIX; i += CCL_TPB) {
        if (lab[i] >= 0) {
            int r = uf_find(lab, i);
            lab[i] = r;
            atomicAdd(&sz[r], 1);
        }
    }
    __syncthreads();

    // dense ids; giant component
    for (int i = t; i < S_PIX; i += CCL_TPB) {
        if (lab[i] == i) {
            int d = atomicAdd(&cnt, 1);
            rid[i] = d;
            atomicMax(&gpack, (sz[i] << 13) | d);
        }
    }
    __syncthreads();

    int* co = cid + b * S_PIX;
    for (int i = t; i < S_PIX; i += CCL_TPB) {
        int l = lab[i];
        co[i] = (l >= 0) ? rid[l] : -1;
    }
    if (t == 0) { ncomp[b] = cnt; gcomp[b] = (gpack >= 0) ? (gpack & 8191) : -1; }
}

// ---------------- K2: streaming accumulate (4 ch/block, 8 loads in flight) ----------------
__global__ __launch_bounds__(TPB, 4) void accum_kernel(
    const float* __restrict__ feat, const float* __restrict__ sn,
    const int* __restrict__ cid, const int* __restrict__ ncomp,
    const int* __restrict__ gcomp, float* __restrict__ pdots)
{
    __shared__ float acc[CPB * MAXC];   // 16 KB
    __shared__ float snc[KP * CPB];
    const int b  = blockIdx.y;
    const int c0 = blockIdx.x * CPB;
    const int t  = threadIdx.x;

    for (int i = t; i < CPB * MAXC; i += TPB) acc[i] = 0.f;
    if (t < KP * CPB) snc[t] = sn[(t >> 2) * NCH + c0 + (t & 3)];
    __syncthreads();

    const int gc = gcomp[b];
    const int wave = t >> 6, lane = t & 63;
    const int4*  cb = reinterpret_cast<const int4*>(cid + b * S_PIX);
    const float4* f4 = reinterpret_cast<const float4*>(
        feat + (size_t)b * NCH * S_PIX + (size_t)c0 * S_PIX);
    float g[CPB] = {0.f, 0.f, 0.f, 0.f};

    auto pe = [&](int c, float e0, float e1, float e2, float e3) {
        if (c == gc) { g[0] += e0; g[1] += e1; g[2] += e2; g[3] += e3; }
        else if (c >= 0) {
            atomicAdd(&acc[c], e0);
            atomicAdd(&acc[MAXC + c], e1);
            atomicAdd(&acc[2 * MAXC + c], e2);
            atomicAdd(&acc[3 * MAXC + c], e3);
        }
    };
    auto proc = [&](const int4& q, const float4 (&v)[CPB]) {
        if ((q.x & q.y & q.z & q.w) == -1) return;
        pe(q.x, v[0].x, v[1].x, v[2].x, v[3].x);
        pe(q.y, v[0].y, v[1].y, v[2].y, v[3].y);
        pe(q.z, v[0].z, v[1].z, v[2].z, v[3].z);
        pe(q.w, v[0].w, v[1].w, v[2].w, v[3].w);
    };

    const int base = wave * 256;   // quad index base for this wave (1024 px)
    #pragma unroll
    for (int it = 0; it < 4; it += 2) {
        const int qi0 = base + it * 64 + lane;
        const int qi1 = qi0 + 64;
        const int4 q0 = cb[qi0];
        const int4 q1 = cb[qi1];
        float4 v0[CPB], v1[CPB];
        #pragma unroll
        for (int h = 0; h < CPB; ++h) v0[h] = f4[h * (S_PIX / 4) + qi0];
        #pragma unroll
        for (int h = 0; h < CPB; ++h) v1[h] = f4[h * (S_PIX / 4) + qi1];
        proc(q0, v0);
        proc(q1, v1);
    }

    #pragma unroll
    for (int m = 32; m >= 1; m >>= 1) {
        #pragma unroll
        for (int h = 0; h < CPB; ++h) g[h] += __shfl_xor(g[h], m);
    }
    if (lane == 0 && gc >= 0) {
        #pragma unroll
        for (int h = 0; h < CPB; ++h) atomicAdd(&acc[h * MAXC + gc], g[h]);
    }
    __syncthreads();

    const int n = ncomp[b];
    for (int j = t; j < n; j += TPB) {
        float s[CPB]; float n2 = 0.f;
        #pragma unroll
        for (int h = 0; h < CPB; ++h) { float x = acc[h * MAXC + j]; s[h] = x; n2 += x * x; }
        float* dst = pdots + (size_t)(b * MAXC + j) * 16;
        #pragma unroll
        for (int kp = 0; kp < KP; ++kp) {
            float d = 0.f;
            #pragma unroll
            for (int h = 0; h < CPB; ++h) d += snc[kp * CPB + h] * s[h];
            atomicAdd(&dst[kp], d);
        }
        atomicAdd(&dst[KP], n2);
    }
}

// ---------------- K3: score ----------------
__global__ __launch_bounds__(TPB) void score_kernel(
    const float* __restrict__ pdots, const int* __restrict__ ncomp,
    float* __restrict__ out)
{
    __shared__ float red[5][TPB];
    const int b = blockIdx.x, t = threadIdx.x;
    const int n = ncomp[b];
    float ak[5] = {0.f, 0.f, 0.f, 0.f, 0.f};
    for (int j = t; j < n; j += TPB) {
        const float* d = pdots + (size_t)(b * MAXC + j) * 16;
        float4 d0 = *(const float4*)(d + 0);
        float4 d1 = *(const float4*)(d + 4);
        float4 d2 = *(const float4*)(d + 8);
        float4 d3 = *(const float4*)(d + 12);
        float inv = 1.f / fmaxf(sqrtf(d3.w), 1e-12f);
        ak[0] += fmaxf(fmaxf(d0.x, d0.y), d0.z) * inv;
        ak[1] += fmaxf(fmaxf(d0.w, d1.x), d1.y) * inv;
        ak[2] += fmaxf(fmaxf(d1.z, d1.w), d2.x) * inv;
        ak[3] += fmaxf(fmaxf(d2.y, d2.z), d2.w) * inv;
        ak[4] += fmaxf(fmaxf(d3.x, d3.y), d3.z) * inv;
    }
    #pragma unroll
    for (int k = 0; k < 5; ++k) red[k][t] = ak[k];
    __syncthreads();
    for (int s = TPB / 2; s > 0; s >>= 1) {
        if (t < s) {
            #pragma unroll
            for (int k = 0; k < 5; ++k) red[k][t] += red[k][t + s];
        }
        __syncthreads();
    }
    if (t < 5) out[b * 5 + t] = red[t][0] / (float)max(n, 1);
}

extern "C" void kernel_launch(void* const* d_in, const int* in_sizes, int n_in,
                              void* d_out, int out_size, void* d_ws, size_t ws_size,
                              hipStream_t stream)
{
    const float* feat = (const float*)d_in[0];
    const int*   mask = (const int*)d_in[1];
    const float* sfc  = (const float*)d_in[2];
    float* out = (float*)d_out;
    char* ws = (char*)d_ws;

    int*   cid   = (int*)ws;                                   // 1 MB
    int*   ncomp = (int*)(ws + 1048576);                       // 256 B
    int*   gcomp = (int*)(ws + 1048576 + 1024);                // 256 B
    float* sn    = (float*)(ws + 1048576 + 2048);              // 15 KB
    float* pdots = (float*)(ws + 1048576 + 2048 + 15360);      // 4 MB

    hipMemsetAsync(pdots, 0, (size_t)NB * MAXC * 16 * 4, stream);
    sfc_norm_kernel<<<1, TPB, 0, stream>>>(sfc, sn);
    ccl_uf_kernel<<<NB, CCL_TPB, 0, stream>>>(mask, cid, ncomp, gcomp);
    accum_kernel<<<dim3(NCHUNK, NB), TPB, 0, stream>>>(feat, sn, cid, ncomp, gcomp, pdots);
    score_kernel<<<NB, TPB, 0, stream>>>(pdots, ncomp, out);
}